// Round 1
// baseline (188730.933 us; speedup 1.0000x reference)
//
#include <hip/hip_runtime.h>

// =====================================================================
// AutoregressiveSubsetSampler — persistent cooperative kernel, MI355X.
//
// 8192 sequential steps; per step a chain of matvecs + 2 layernorms + a
// Bernoulli row-sampling branch. Strategy:
//   * 64 WGs x 256 thr, all weights row-sliced into LDS (~150 KB/WG, 1 WG/CU).
//   * Custom agent-scope spin barrier; 4 barriers per step on the critical
//     path (h1 -> px -> f1 -> pg). LayerNorms recomputed redundantly per WG.
//   * Attention/Wg/W2 chain folded offline (per launch) into one matrix:
//       pre_ln1 = Awg @ h1 + c3,  Awg = (I + Wo@Wv) @ (Wg @ W2)  (fp64 prep).
//   * ALL accumulation in fp64 (weights are exact fp32 values promoted):
//     output is binary (u < sigmoid(logits)), so logits must match the
//     numpy reference to ~1e-9 or samples flip. Counts via exact u32 atomics.
// =====================================================================

typedef unsigned int u32;

#define NWG   64
#define NT    256
#define NSTEP 8192

// ---------------------------------------------------------------------
// agent-scope grid barrier: single counter + monotone epoch flag.
// cnt at hdr[0], flag at hdr[32] (separate cachelines), counts at hdr[48..55].
// ---------------------------------------------------------------------
__device__ __forceinline__ void gbar(u32* cnt, u32* flg, u32 e) {
  __syncthreads();  // drains this WG's global stores (vmcnt 0) into L2
  if (threadIdx.x == 0) {
    u32 prev = __hip_atomic_fetch_add(cnt, 1u, __ATOMIC_ACQ_REL, __HIP_MEMORY_SCOPE_AGENT);
    if (prev == e * (u32)NWG - 1u) {
      __hip_atomic_store(flg, e, __ATOMIC_RELEASE, __HIP_MEMORY_SCOPE_AGENT);
    } else {
      while (__hip_atomic_load(flg, __ATOMIC_ACQUIRE, __HIP_MEMORY_SCOPE_AGENT) < e) { }
    }
  }
  __syncthreads();
}

// block-wide sum of one double per thread (256 threads, deterministic order)
__device__ __forceinline__ double block_sum(double v, double* sred) {
  #pragma unroll
  for (int off = 32; off; off >>= 1) v += __shfl_down(v, off);
  __syncthreads();                       // protect sred from previous use
  if ((threadIdx.x & 63) == 0) sred[threadIdx.x >> 6] = v;
  __syncthreads();
  return sred[0] + sred[1] + sred[2] + sred[3];
}

// ---------------------------------------------------------------------
// prep kernels (run every launch; ~100us total, fp64)
// ---------------------------------------------------------------------
__global__ void prep_zero(u32* hdr) {
  int i = threadIdx.x;
  if (i < 64) hdr[i] = 0u;   // cnt, flag, counts[2][4], padding
}

// Wg2 = Wg @ W2   [256x512];  c1 = Wg@b2 + bg
__global__ __launch_bounds__(256) void prep_mm1(const float* __restrict__ Wg,
    const float* __restrict__ W2, const float* __restrict__ b2,
    const float* __restrict__ bg, double* __restrict__ Wg2d, double* __restrict__ c1d) {
  int i = threadIdx.x, j = blockIdx.x;          // i: row 0..255, j: col 0..511
  double acc = 0.0;
  for (int k = 0; k < 256; k++) acc += (double)Wg[i * 256 + k] * (double)W2[k * 512 + j];
  Wg2d[(size_t)i * 512 + j] = acc;
  if (j == 0) {
    double c = 0.0;
    for (int k = 0; k < 256; k++) c += (double)Wg[i * 256 + k] * (double)b2[k];
    c1d[i] = c + (double)bg[i];
  }
}

// Wov = Wo @ Wv  [256x256];  c2 = Wo@bv + bo
__global__ __launch_bounds__(256) void prep_mm2(const float* __restrict__ Wo,
    const float* __restrict__ Wv, const float* __restrict__ bv,
    const float* __restrict__ bo, double* __restrict__ Wovd, double* __restrict__ c2d) {
  int i = threadIdx.x, j = blockIdx.x;
  double acc = 0.0;
  for (int k = 0; k < 256; k++) acc += (double)Wo[i * 256 + k] * (double)Wv[k * 256 + j];
  Wovd[i * 256 + j] = acc;
  if (j == 0) {
    double c = 0.0;
    for (int k = 0; k < 256; k++) c += (double)Wo[i * 256 + k] * (double)bv[k];
    c2d[i] = c + (double)bo[i];
  }
}

// Awg = (I + Wov) @ Wg2  [256x512];  c3 = (I+Wov)@c1 + c2
__global__ __launch_bounds__(256) void prep_mm3(const double* __restrict__ Wg2d,
    const double* __restrict__ Wovd, const double* __restrict__ c1d,
    const double* __restrict__ c2d, double* __restrict__ Awgd, double* __restrict__ c3d) {
  int i = threadIdx.x, j = blockIdx.x;
  double acc = Wg2d[(size_t)i * 512 + j];
  for (int k = 0; k < 256; k++) acc += Wovd[i * 256 + k] * Wg2d[(size_t)k * 512 + j];
  Awgd[(size_t)i * 512 + j] = acc;
  if (j == 0) {
    double c = c1d[i] + c2d[i];
    for (int k = 0; k < 256; k++) c += Wovd[i * 256 + k] * c1d[k];
    c3d[i] = c;
  }
}

// ---------------------------------------------------------------------
// main persistent kernel: 64 WGs x 256 threads, 8192 steps, 4 barriers/step
// ---------------------------------------------------------------------
__global__ __launch_bounds__(256) void sampler_main(
    const float* __restrict__ gnn, const float* __restrict__ u,
    const float* __restrict__ W1, const float* __restrict__ b1,
    const float* __restrict__ W2, const float* __restrict__ b2,
    const float* __restrict__ Wr, const float* __restrict__ br,
    const float* __restrict__ Wf1, const float* __restrict__ bf1,
    const float* __restrict__ Wf2, const float* __restrict__ bf2,
    const float* __restrict__ ln1g, const float* __restrict__ ln1b,
    const float* __restrict__ ln2g, const float* __restrict__ ln2b,
    const double* __restrict__ Awgd, const double* __restrict__ c3d,
    double* __restrict__ h1buf, double* __restrict__ pxbuf,
    double* __restrict__ hdbuf, double* __restrict__ f1buf,
    double* __restrict__ pgbuf, u32* __restrict__ hdr,
    float* __restrict__ out) {

  // LDS: weight slices fp32 (+1 pad to break bank strides), vectors fp64.
  // Total ~150 KB -> 1 WG/CU.
  __shared__ float sW1 [8  * 513];   // W1 rows  8b..8b+7   (512 cols)
  __shared__ float sW2 [4  * 513];   // W2 rows  4b..4b+3   (512 cols)
  __shared__ float sWf1[32 * 257];   // Wf1 rows 32b..      (256 cols)
  __shared__ float sWr [32 * 257];   // Wr rows  32b..      (256 cols)
  __shared__ float sWf2[4  * 2049];  // Wf2 rows 4b..       (2048 cols)
  __shared__ double sin_[512];       // [ m_t ; g ]
  __shared__ double svec[512];       // staging: h1 (S2) then h-fp64 (S3)
  __shared__ double sx  [256];       // x = ln1(px)
  __shared__ double sf1 [2048];      // f1 staging (S4)
  __shared__ double sprob[32];       // probs for my 32 row-cols
  __shared__ double sred[8];
  __shared__ u32 ssamp[4];           // sample bitmask per attempt (my 32 cols)
  __shared__ int sidx;

  const int b = blockIdx.x, tid = threadIdx.x;
  u32* cnt = &hdr[0];
  u32* flg = &hdr[32];
  u32* counts = &hdr[48];            // [2][4] u32, double-buffered by step parity

  // ---- load weight slices into LDS ----
  for (int r = 0; r < 8; r++)
    for (int c = tid; c < 512; c += NT) sW1[r * 513 + c] = W1[(8 * b + r) * 512 + c];
  for (int r = 0; r < 4; r++)
    for (int c = tid; c < 512; c += NT) sW2[r * 513 + c] = W2[(4 * b + r) * 512 + c];
  for (int r = 0; r < 32; r++)
    for (int c = tid; c < 256; c += NT) sWf1[r * 257 + c] = Wf1[(32 * b + r) * 256 + c];
  for (int r = 0; r < 32; r++)
    for (int c = tid; c < 256; c += NT) sWr[r * 257 + c] = Wr[(32 * b + r) * 256 + c];
  for (int r = 0; r < 4; r++)
    for (int c = tid; c < 2048; c += NT) sWf2[r * 2049 + c] = Wf2[(4 * b + r) * 2048 + c];

  // initial state: m(0) = gnn row 0, g0 = 0
  sin_[tid]       = (double)gnn[tid];
  sin_[256 + tid] = 0.0;

  // per-thread constants (registers; avoids LDS for params)
  const double ln1gv = (double)ln1g[tid], ln1bv = (double)ln1b[tid];
  const double ln2gv = (double)ln2g[tid], ln2bv = (double)ln2b[tid];
  const double b1v  = (double)b1 [8  * b + (tid >> 5)];
  const double b2v  = (double)b2 [4  * b + (tid >> 6)];
  const double c3v  =          c3d[4  * b + (tid >> 6)];
  const double bf1v = (double)bf1[32 * b + (tid >> 3)];
  const double brv  = (double)br [32 * b + (tid >> 3)];
  const double bf2v = (double)bf2[4  * b + (tid >> 6)];
  __syncthreads();

  u32 ep = 0;
  for (int t = 0; t < NSTEP; ++t) {
    // ================= S1: h1 = relu(W1 @ [m;g] + b1), rows 8b..8b+7 ======
    {
      int r = tid >> 5, lane = tid & 31;
      const float* wrow = &sW1[r * 513];
      double acc = 0.0;
      #pragma unroll
      for (int k = 0; k < 16; k++) { int j = lane + 32 * k; acc += (double)wrow[j] * sin_[j]; }
      #pragma unroll
      for (int off = 16; off; off >>= 1) acc += __shfl_down(acc, off, 32);
      if (lane == 0) { double v = acc + b1v; h1buf[8 * b + r] = (v > 0.0) ? v : 0.0; }
    }
    // prefetch u(t) for this WG's 32 columns x 4 attempts
    float ureg = 0.0f;
    if (tid < 128) {
      int a = tid >> 5, jj = tid & 31;
      ureg = u[((size_t)t * 4 + a) * 2048 + 32 * b + jj];
    }
    // zero next step's count buffer (its readers finished at B4(t-1))
    if (b == 0 && tid == 0) {
      u32* cz = &counts[((t + 1) & 1) * 4];
      for (int a = 0; a < 4; a++)
        __hip_atomic_store(&cz[a], 0u, __ATOMIC_RELAXED, __HIP_MEMORY_SCOPE_AGENT);
    }
    gbar(cnt, flg, ++ep);   // B1: h1 published

    // ================= S2: px = Awg@h1 + c3 ; h = W2@h1 + b2 (fp64) =======
    svec[tid] = h1buf[tid]; svec[tid + 256] = h1buf[tid + 256];
    __syncthreads();
    {
      int w = tid >> 6, lane = tid & 63;
      const double* arow = &Awgd[(size_t)(4 * b + w) * 512];
      const float* w2row = &sW2[w * 513];
      double accA = 0.0, accH = 0.0;
      #pragma unroll
      for (int k = 0; k < 8; k++) {
        int j = lane + 64 * k; double hv = svec[j];
        accA += arow[j] * hv; accH += (double)w2row[j] * hv;
      }
      #pragma unroll
      for (int off = 32; off; off >>= 1) { accA += __shfl_down(accA, off); accH += __shfl_down(accH, off); }
      if (lane == 0) { pxbuf[4 * b + w] = accA + c3v; hdbuf[4 * b + w] = accH + b2v; }
    }
    // prefetch m(t+1) (sin_ lower half free after B1)
    sin_[tid] = (double)gnn[(size_t)((t + 1) & 4095) * 256 + tid];
    gbar(cnt, flg, ++ep);   // B2: px, h published

    // ================= S3: ln1 (redundant), f1 slice, logits slice ========
    {
      double pxv = pxbuf[tid];
      double mu  = block_sum(pxv, sred) * (1.0 / 256.0);
      double dv  = pxv - mu;
      double var = block_sum(dv * dv, sred) * (1.0 / 256.0);
      double rs  = 1.0 / sqrt(var + 1e-5);
      sx[tid] = dv * rs * ln1gv + ln1bv;
    }
    svec[tid] = hdbuf[tid];          // h (fp64) into LDS (reuse svec[0:256])
    __syncthreads();
    {
      int rr = tid >> 3, lane = tid & 7;
      const float* f1row = &sWf1[rr * 257];
      const float* wrrow = &sWr [rr * 257];
      double accF = 0.0, accL = 0.0;
      #pragma unroll
      for (int k = 0; k < 32; k++) {
        int j = lane + 8 * k;
        accF += (double)f1row[j] * sx[j];
        accL += (double)wrrow[j] * svec[j];
      }
      #pragma unroll
      for (int off = 4; off; off >>= 1) { accF += __shfl_down(accF, off, 8); accL += __shfl_down(accL, off, 8); }
      if (lane == 0) {
        double fv = accF + bf1v;
        f1buf[32 * b + rr] = (fv > 0.0) ? fv : 0.0;
        double L = accL + brv;
        sprob[rr] = 1.0 / (1.0 + exp(-L));       // fp64 sigmoid
      }
    }
    __syncthreads();
    if (tid < 128) {                  // samples + exact integer counts
      int a = tid >> 5, jj = tid & 31;
      bool pred = ((double)ureg < sprob[jj]);    // strict <, fp64, matches ref
      unsigned long long bal = __ballot(pred);
      int l64 = tid & 63;
      if (l64 == 0) {
        u32 mm = (u32)(bal & 0xffffffffull);
        ssamp[a] = mm; atomicAdd(&counts[(t & 1) * 4 + a], (u32)__popc(mm));
      } else if (l64 == 32) {
        u32 mm = (u32)(bal >> 32);
        ssamp[a] = mm; atomicAdd(&counts[(t & 1) * 4 + a], (u32)__popc(mm));
      }
    }
    gbar(cnt, flg, ++ep);   // B3: f1, counts published

    // ================= S4: pg = x + Wf2@f1 + bf2 ; emit row ===============
    if (tid == 0) {
      u32 c[4];
      for (int a = 0; a < 4; a++)
        c[a] = __hip_atomic_load(&counts[(t & 1) * 4 + a], __ATOMIC_RELAXED, __HIP_MEMORY_SCOPE_AGENT);
      int idx = 0;
      for (int a = 3; a >= 0; a--) {   // first valid attempt, else 0
        bool va = (c[a] == 0u) || (c[a] >= 2u && c[a] <= 6u);
        if (va) idx = a;
      }
      sidx = idx;
    }
    for (int j = tid; j < 2048; j += NT) sf1[j] = f1buf[j];
    __syncthreads();
    {
      int w = tid >> 6, lane = tid & 63;
      const float* frow = &sWf2[w * 2049];
      double acc = 0.0;
      #pragma unroll
      for (int k = 0; k < 32; k++) { int j = lane + 64 * k; acc += (double)frow[j] * sf1[j]; }
      #pragma unroll
      for (int off = 32; off; off >>= 1) acc += __shfl_down(acc, off);
      if (lane == 0) pgbuf[4 * b + w] = acc + sx[4 * b + w] + bf2v;
    }
    if (tid < 32) {                    // write selected attempt's row slice
      u32 mm = ssamp[sidx];
      out[(size_t)t * 2048 + 32 * b + tid] = ((mm >> tid) & 1u) ? 1.0f : 0.0f;
    }
    gbar(cnt, flg, ++ep);   // B4: pg published

    // ================= S5: g = ln2(pg) (redundant per WG) =================
    {
      double pgv = pgbuf[tid];
      double mu  = block_sum(pgv, sred) * (1.0 / 256.0);
      double dv  = pgv - mu;
      double var = block_sum(dv * dv, sred) * (1.0 / 256.0);
      double rs  = 1.0 / sqrt(var + 1e-5);
      sin_[256 + tid] = dv * rs * ln2gv + ln2bv;
    }
    __syncthreads();
  }
}

// ---------------------------------------------------------------------
extern "C" void kernel_launch(void* const* d_in, const int* in_sizes, int n_in,
                              void* d_out, int out_size, void* d_ws, size_t ws_size,
                              hipStream_t stream) {
  const float* gnn = (const float*)d_in[0];
  // d_in[1] ('b') unused by the reference output
  const float* u   = (const float*)d_in[2];
  const float* W1  = (const float*)d_in[3];
  const float* b1  = (const float*)d_in[4];
  const float* W2  = (const float*)d_in[5];
  const float* b2  = (const float*)d_in[6];
  const float* Wr  = (const float*)d_in[7];
  const float* br  = (const float*)d_in[8];
  const float* Wg  = (const float*)d_in[9];
  const float* bg  = (const float*)d_in[10];
  const float* Wv  = (const float*)d_in[11];
  const float* bv  = (const float*)d_in[12];
  const float* Wo  = (const float*)d_in[13];
  const float* bo  = (const float*)d_in[14];
  const float* Wf1 = (const float*)d_in[15];
  const float* bf1 = (const float*)d_in[16];
  const float* Wf2 = (const float*)d_in[17];
  const float* bf2 = (const float*)d_in[18];
  const float* ln1g = (const float*)d_in[19];
  const float* ln1b = (const float*)d_in[20];
  const float* ln2g = (const float*)d_in[21];
  const float* ln2b = (const float*)d_in[22];
  float* out = (float*)d_out;

  // workspace layout (~2.6 MB)
  u32* hdr = (u32*)d_ws;                          // 256 B header
  double* base  = (double*)((char*)d_ws + 256);
  double* h1buf = base;            // 512
  double* pxbuf = h1buf + 512;     // 256
  double* hdbuf = pxbuf + 256;     // 256
  double* f1buf = hdbuf + 256;     // 2048
  double* pgbuf = f1buf + 2048;    // 256
  double* c1d   = pgbuf + 256;     // 256
  double* c2d   = c1d + 256;       // 256
  double* c3d   = c2d + 256;       // 256
  double* Wg2d  = c3d + 256;       // 131072
  double* Wovd  = Wg2d + 131072;   // 65536
  double* Awgd  = Wovd + 65536;    // 131072

  hipLaunchKernelGGL(prep_zero, dim3(1), dim3(64), 0, stream, hdr);
  hipLaunchKernelGGL(prep_mm1, dim3(512), dim3(256), 0, stream, Wg, W2, b2, bg, Wg2d, c1d);
  hipLaunchKernelGGL(prep_mm2, dim3(256), dim3(256), 0, stream, Wo, Wv, bv, bo, Wovd, c2d);
  hipLaunchKernelGGL(prep_mm3, dim3(512), dim3(256), 0, stream, Wg2d, Wovd, c1d, c2d, Awgd, c3d);
  hipLaunchKernelGGL(sampler_main, dim3(NWG), dim3(NT), 0, stream,
                     gnn, u, W1, b1, W2, b2, Wr, br, Wf1, bf1, Wf2, bf2,
                     ln1g, ln1b, ln2g, ln2b, Awgd, c3d,
                     h1buf, pxbuf, hdbuf, f1buf, pgbuf, hdr, out);
}

// Round 2
// 133293.042 us; speedup vs baseline: 1.4159x; 1.4159x over previous
//
#include <hip/hip_runtime.h>

// =====================================================================
// AutoregressiveSubsetSampler — persistent cooperative kernel, MI355X.
// Round 2: flag-array grid barrier (no atomics) + register-resident
// weight slices (no LDS weight arrays -> no bank conflicts) + relaxed
// agent-scope atomic exchange (release fence has nothing to flush).
//
//   * 64 WGs x 256 thr; per-thread weight slices preloaded to VGPRs.
//   * 4 grid barriers per step (h1 -> px/h -> f1/samples -> pg).
//   * All accumulation fp64 (output is binary u<sigmoid(logit): logits
//     must match numpy ref to ~1e-9 or samples flip).
// =====================================================================

typedef unsigned int u32;

#define NWG   64
#define NT    256
#define NSTEP 8192

// ---- cross-WG exchange: relaxed agent-scope atomics (LLC-coherent) ----
__device__ __forceinline__ double gld(const double* p) {
  return __hip_atomic_load(p, __ATOMIC_RELAXED, __HIP_MEMORY_SCOPE_AGENT);
}
__device__ __forceinline__ void gst(double* p, double v) {
  __hip_atomic_store(p, v, __ATOMIC_RELAXED, __HIP_MEMORY_SCOPE_AGENT);
}
__device__ __forceinline__ u32 gldu(const u32* p) {
  return __hip_atomic_load(p, __ATOMIC_RELAXED, __HIP_MEMORY_SCOPE_AGENT);
}

// ---- flag-array grid barrier: WG b stores flags[b*32]=e (release); ----
// ---- first wave polls all 64 flags in parallel (acquire).          ----
__device__ __forceinline__ void gbar(u32* flags, u32 e) {
  __syncthreads();
  if (threadIdx.x == 0)
    __hip_atomic_store(&flags[blockIdx.x * 32], e, __ATOMIC_RELEASE, __HIP_MEMORY_SCOPE_AGENT);
  if (threadIdx.x < 64) {
    while (__hip_atomic_load(&flags[threadIdx.x * 32], __ATOMIC_ACQUIRE,
                             __HIP_MEMORY_SCOPE_AGENT) < e) { }
  }
  __syncthreads();
}

// block-wide sum of one double per thread (256 threads, deterministic order)
__device__ __forceinline__ double block_sum(double v, double* sred) {
  #pragma unroll
  for (int off = 32; off; off >>= 1) v += __shfl_down(v, off);
  __syncthreads();
  if ((threadIdx.x & 63) == 0) sred[threadIdx.x >> 6] = v;
  __syncthreads();
  return sred[0] + sred[1] + sred[2] + sred[3];
}

// ---------------------------------------------------------------------
// prep kernels (every launch; ~100us, fp64)
// ---------------------------------------------------------------------
__global__ void prep_zero(u32* hdr) {
  int i = blockIdx.x * 256 + threadIdx.x;
  if (i < 4096) hdr[i] = 0u;   // flags[64*32] + counts[8*32] + pad
}

// Wg2 = Wg @ W2   [256x512];  c1 = Wg@b2 + bg
__global__ __launch_bounds__(256) void prep_mm1(const float* __restrict__ Wg,
    const float* __restrict__ W2, const float* __restrict__ b2,
    const float* __restrict__ bg, double* __restrict__ Wg2d, double* __restrict__ c1d) {
  int i = threadIdx.x, j = blockIdx.x;
  double acc = 0.0;
  for (int k = 0; k < 256; k++) acc += (double)Wg[i * 256 + k] * (double)W2[k * 512 + j];
  Wg2d[(size_t)i * 512 + j] = acc;
  if (j == 0) {
    double c = 0.0;
    for (int k = 0; k < 256; k++) c += (double)Wg[i * 256 + k] * (double)b2[k];
    c1d[i] = c + (double)bg[i];
  }
}

// Wov = Wo @ Wv  [256x256];  c2 = Wo@bv + bo
__global__ __launch_bounds__(256) void prep_mm2(const float* __restrict__ Wo,
    const float* __restrict__ Wv, const float* __restrict__ bv,
    const float* __restrict__ bo, double* __restrict__ Wovd, double* __restrict__ c2d) {
  int i = threadIdx.x, j = blockIdx.x;
  double acc = 0.0;
  for (int k = 0; k < 256; k++) acc += (double)Wo[i * 256 + k] * (double)Wv[k * 256 + j];
  Wovd[i * 256 + j] = acc;
  if (j == 0) {
    double c = 0.0;
    for (int k = 0; k < 256; k++) c += (double)Wo[i * 256 + k] * (double)bv[k];
    c2d[i] = c + (double)bo[i];
  }
}

// Awg = (I + Wov) @ Wg2  [256x512];  c3 = (I+Wov)@c1 + c2
__global__ __launch_bounds__(256) void prep_mm3(const double* __restrict__ Wg2d,
    const double* __restrict__ Wovd, const double* __restrict__ c1d,
    const double* __restrict__ c2d, double* __restrict__ Awgd, double* __restrict__ c3d) {
  int i = threadIdx.x, j = blockIdx.x;
  double acc = Wg2d[(size_t)i * 512 + j];
  for (int k = 0; k < 256; k++) acc += Wovd[i * 256 + k] * Wg2d[(size_t)k * 512 + j];
  Awgd[(size_t)i * 512 + j] = acc;
  if (j == 0) {
    double c = c1d[i] + c2d[i];
    for (int k = 0; k < 256; k++) c += Wovd[i * 256 + k] * c1d[k];
    c3d[i] = c;
  }
}

// ---------------------------------------------------------------------
// main persistent kernel: 64 WGs x 256 threads, 8192 steps, 4 barriers/step
// ---------------------------------------------------------------------
__global__ __launch_bounds__(256) void sampler_main(
    const float* __restrict__ gnn, const float* __restrict__ u,
    const float* __restrict__ W1, const float* __restrict__ b1,
    const float* __restrict__ W2, const float* __restrict__ b2,
    const float* __restrict__ Wr, const float* __restrict__ br,
    const float* __restrict__ Wf1, const float* __restrict__ bf1,
    const float* __restrict__ Wf2, const float* __restrict__ bf2,
    const float* __restrict__ ln1g, const float* __restrict__ ln1b,
    const float* __restrict__ ln2g, const float* __restrict__ ln2b,
    const double* __restrict__ Awgd, const double* __restrict__ c3d,
    double* __restrict__ h1buf, double* __restrict__ pxbuf,
    double* __restrict__ hdbuf, double* __restrict__ f1buf,
    double* __restrict__ pgbuf, u32* __restrict__ hdr,
    float* __restrict__ out) {

  __shared__ double sin_[512];       // [ m_t ; g ]
  __shared__ double svec[512];       // staging: h1 (S2) then h (S3)
  __shared__ double sx  [256];       // x = ln1(px)
  __shared__ double sf1 [2048];      // f1 staging (S4)
  __shared__ double sprob[32];
  __shared__ double sred[8];
  __shared__ u32 ssamp[4];
  __shared__ int sidx;

  const int b = blockIdx.x, tid = threadIdx.x;
  u32* flags  = hdr;                 // 64 x 32 u32 (128B stride)
  u32* counts = hdr + 2048;          // [2][4] x 32-stride u32

  // ---- per-thread weight slices -> registers (compile-time indexed) ----
  const int r1 = tid >> 5, l1 = tid & 31;     // S1: row 8b+r1
  float w1reg[16];
  #pragma unroll
  for (int k = 0; k < 16; k++) w1reg[k] = W1[(size_t)(8 * b + r1) * 512 + l1 + 32 * k];

  const int w2i = tid >> 6, l2 = tid & 63;    // S2/S4: row 4b+w2i
  double areg[8]; float w2reg[8];
  #pragma unroll
  for (int k = 0; k < 8; k++) {
    areg[k]  = Awgd[(size_t)(4 * b + w2i) * 512 + l2 + 64 * k];
    w2reg[k] = W2  [(size_t)(4 * b + w2i) * 512 + l2 + 64 * k];
  }
  const int r3 = tid >> 3, l3 = tid & 7;      // S3: row 32b+r3
  float f1reg[32], wrreg[32];
  #pragma unroll
  for (int k = 0; k < 32; k++) {
    f1reg[k] = Wf1[(size_t)(32 * b + r3) * 256 + l3 + 8 * k];
    wrreg[k] = Wr [(size_t)(32 * b + r3) * 256 + l3 + 8 * k];
  }
  float f2reg[32];
  #pragma unroll
  for (int k = 0; k < 32; k++) f2reg[k] = Wf2[(size_t)(4 * b + w2i) * 2048 + l2 + 64 * k];

  // per-thread constants
  const double ln1gv = (double)ln1g[tid], ln1bv = (double)ln1b[tid];
  const double ln2gv = (double)ln2g[tid], ln2bv = (double)ln2b[tid];
  const double b1v  = (double)b1 [8  * b + r1];
  const double b2v  = (double)b2 [4  * b + w2i];
  const double c3v  =          c3d[4  * b + w2i];
  const double bf1v = (double)bf1[32 * b + r3];
  const double brv  = (double)br [32 * b + r3];
  const double bf2v = (double)bf2[4  * b + w2i];

  // initial state: m(0) = gnn row 0, g0 = 0
  sin_[tid]       = (double)gnn[tid];
  sin_[256 + tid] = 0.0;
  __syncthreads();

  u32 ep = 0;
  for (int t = 0; t < NSTEP; ++t) {
    // ===== S1: h1 = relu(W1 @ [m;g] + b1), rows 8b..8b+7 =====
    {
      double acc = 0.0;
      #pragma unroll
      for (int k = 0; k < 16; k++) acc += (double)w1reg[k] * sin_[l1 + 32 * k];
      #pragma unroll
      for (int off = 16; off; off >>= 1) acc += __shfl_down(acc, off, 32);
      if (l1 == 0) { double v = acc + b1v; gst(&h1buf[8 * b + r1], (v > 0.0) ? v : 0.0); }
    }
    // prefetch u(t): this WG's 32 cols x 4 attempts
    float ureg = 0.0f;
    if (tid < 128) {
      int a = tid >> 5, jj = tid & 31;
      ureg = u[((size_t)t * 4 + a) * 2048 + 32 * b + jj];
    }
    // zero next parity's counters (readers done at B4(t-1))
    if (b == 0 && tid < 4)
      __hip_atomic_store(&counts[(((t + 1) & 1) * 4 + tid) * 32], 0u,
                         __ATOMIC_RELAXED, __HIP_MEMORY_SCOPE_AGENT);
    gbar(flags, ++ep);   // B1: h1 published

    // ===== S2: px = Awg@h1 + c3 ; h = W2@h1 + b2 =====
    svec[tid] = gld(&h1buf[tid]); svec[tid + 256] = gld(&h1buf[tid + 256]);
    __syncthreads();
    {
      double accA = 0.0, accH = 0.0;
      #pragma unroll
      for (int k = 0; k < 8; k++) {
        double hv = svec[l2 + 64 * k];
        accA += areg[k] * hv; accH += (double)w2reg[k] * hv;
      }
      #pragma unroll
      for (int off = 32; off; off >>= 1) { accA += __shfl_down(accA, off); accH += __shfl_down(accH, off); }
      if (l2 == 0) { gst(&pxbuf[4 * b + w2i], accA + c3v); gst(&hdbuf[4 * b + w2i], accH + b2v); }
    }
    sin_[tid] = (double)gnn[(size_t)((t + 1) & 4095) * 256 + tid];  // m(t+1)
    gbar(flags, ++ep);   // B2: px, h published

    // ===== S3: ln1 (redundant per WG), f1 slice, logits slice =====
    {
      double pxv = gld(&pxbuf[tid]);
      double mu  = block_sum(pxv, sred) * (1.0 / 256.0);
      double dv  = pxv - mu;
      double var = block_sum(dv * dv, sred) * (1.0 / 256.0);
      double rs  = 1.0 / sqrt(var + 1e-5);
      sx[tid] = dv * rs * ln1gv + ln1bv;
    }
    svec[tid] = gld(&hdbuf[tid]);
    __syncthreads();
    {
      double accF = 0.0, accL = 0.0;
      #pragma unroll
      for (int k = 0; k < 32; k++) {
        int j = l3 + 8 * k;
        accF += (double)f1reg[k] * sx[j];
        accL += (double)wrreg[k] * svec[j];
      }
      #pragma unroll
      for (int off = 4; off; off >>= 1) { accF += __shfl_down(accF, off, 8); accL += __shfl_down(accL, off, 8); }
      if (l3 == 0) {
        double fv = accF + bf1v;
        gst(&f1buf[32 * b + r3], (fv > 0.0) ? fv : 0.0);
        sprob[r3] = 1.0 / (1.0 + exp(-(accL + brv)));
      }
    }
    __syncthreads();
    if (tid < 128) {                  // samples + exact integer counts
      int a = tid >> 5;
      bool pred = ((double)ureg < sprob[tid & 31]);
      unsigned long long bal = __ballot(pred);
      int l64 = tid & 63;
      if (l64 == 0) {
        u32 mm = (u32)(bal & 0xffffffffull);
        ssamp[a] = mm; atomicAdd(&counts[((t & 1) * 4 + a) * 32], (u32)__popc(mm));
      } else if (l64 == 32) {
        u32 mm = (u32)(bal >> 32);
        ssamp[a] = mm; atomicAdd(&counts[((t & 1) * 4 + a) * 32], (u32)__popc(mm));
      }
    }
    gbar(flags, ++ep);   // B3: f1, counts published

    // ===== S4: pg = x + Wf2@f1 + bf2 ; emit row =====
    if (tid == 0) {
      int idx = 0;
      for (int a = 3; a >= 0; a--) {
        u32 c = gldu(&counts[((t & 1) * 4 + a) * 32]);
        bool va = (c == 0u) || (c >= 2u && c <= 6u);
        if (va) idx = a;
      }
      sidx = idx;
    }
    {
      double tmp[8];
      #pragma unroll
      for (int k = 0; k < 8; k++) tmp[k] = gld(&f1buf[tid + 256 * k]);
      #pragma unroll
      for (int k = 0; k < 8; k++) sf1[tid + 256 * k] = tmp[k];
    }
    __syncthreads();
    {
      double acc = 0.0;
      #pragma unroll
      for (int k = 0; k < 32; k++) acc += (double)f2reg[k] * sf1[l2 + 64 * k];
      #pragma unroll
      for (int off = 32; off; off >>= 1) acc += __shfl_down(acc, off);
      if (l2 == 0) gst(&pgbuf[4 * b + w2i], acc + sx[4 * b + w2i] + bf2v);
    }
    if (tid < 32) {
      u32 mm = ssamp[sidx];
      out[(size_t)t * 2048 + 32 * b + tid] = ((mm >> tid) & 1u) ? 1.0f : 0.0f;
    }
    gbar(flags, ++ep);   // B4: pg published

    // ===== S5: g = ln2(pg) (redundant per WG) =====
    {
      double pgv = gld(&pgbuf[tid]);
      double mu  = block_sum(pgv, sred) * (1.0 / 256.0);
      double dv  = pgv - mu;
      double var = block_sum(dv * dv, sred) * (1.0 / 256.0);
      double rs  = 1.0 / sqrt(var + 1e-5);
      sin_[256 + tid] = dv * rs * ln2gv + ln2bv;
    }
    __syncthreads();
  }
}

// ---------------------------------------------------------------------
extern "C" void kernel_launch(void* const* d_in, const int* in_sizes, int n_in,
                              void* d_out, int out_size, void* d_ws, size_t ws_size,
                              hipStream_t stream) {
  const float* gnn = (const float*)d_in[0];
  const float* u   = (const float*)d_in[2];
  const float* W1  = (const float*)d_in[3];
  const float* b1  = (const float*)d_in[4];
  const float* W2  = (const float*)d_in[5];
  const float* b2  = (const float*)d_in[6];
  const float* Wr  = (const float*)d_in[7];
  const float* br  = (const float*)d_in[8];
  const float* Wg  = (const float*)d_in[9];
  const float* bg  = (const float*)d_in[10];
  const float* Wv  = (const float*)d_in[11];
  const float* bv  = (const float*)d_in[12];
  const float* Wo  = (const float*)d_in[13];
  const float* bo  = (const float*)d_in[14];
  const float* Wf1 = (const float*)d_in[15];
  const float* bf1 = (const float*)d_in[16];
  const float* Wf2 = (const float*)d_in[17];
  const float* bf2 = (const float*)d_in[18];
  const float* ln1g = (const float*)d_in[19];
  const float* ln1b = (const float*)d_in[20];
  const float* ln2g = (const float*)d_in[21];
  const float* ln2b = (const float*)d_in[22];
  float* out = (float*)d_out;

  // workspace: 16KB header (flags+counts), then fp64 buffers
  u32* hdr = (u32*)d_ws;
  double* base  = (double*)((char*)d_ws + 16384);
  double* h1buf = base;            // 512
  double* pxbuf = h1buf + 512;     // 256
  double* hdbuf = pxbuf + 256;     // 256
  double* f1buf = hdbuf + 256;     // 2048
  double* pgbuf = f1buf + 2048;    // 256
  double* c1d   = pgbuf + 256;     // 256
  double* c2d   = c1d + 256;       // 256
  double* c3d   = c2d + 256;       // 256
  double* Wg2d  = c3d + 256;       // 131072
  double* Wovd  = Wg2d + 131072;   // 65536
  double* Awgd  = Wovd + 65536;    // 131072

  hipLaunchKernelGGL(prep_zero, dim3(16), dim3(256), 0, stream, hdr);
  hipLaunchKernelGGL(prep_mm1, dim3(512), dim3(256), 0, stream, Wg, W2, b2, bg, Wg2d, c1d);
  hipLaunchKernelGGL(prep_mm2, dim3(256), dim3(256), 0, stream, Wo, Wv, bv, bo, Wovd, c2d);
  hipLaunchKernelGGL(prep_mm3, dim3(512), dim3(256), 0, stream, Wg2d, Wovd, c1d, c2d, Awgd, c3d);
  hipLaunchKernelGGL(sampler_main, dim3(NWG), dim3(NT), 0, stream,
                     gnn, u, W1, b1, W2, b2, Wr, br, Wf1, bf1, Wf2, bf2,
                     ln1g, ln1b, ln2g, ln2b, Awgd, c3d,
                     h1buf, pxbuf, hdbuf, f1buf, pgbuf, hdr, out);
}

// Round 3
// 109661.951 us; speedup vs baseline: 1.7210x; 1.2155x over previous
//
#include <hip/hip_runtime.h>

// =====================================================================
// AutoregressiveSubsetSampler — persistent cooperative kernel, MI355X.
// Round 3: invalidate-free grid barrier. All cross-WG exchange uses
// agent-scope (sc1, cache-bypassing) relaxed atomics, so no acquire
// invalidates / release writebacks are needed anywhere:
//   arrival  = relaxed fetch_add (after __syncthreads, which drains vmcnt)
//   detect   = last arriver relaxed-stores epoch to ONE broadcast word
//   wait     = single lane spins with RELAXED loads on that one line
// R2's poll did an acquire (L1/L2 invalidate) per iteration across 64
// cachelines per WG — the 16 us/step stall + 2.1 GB FETCH both trace there.
//
//   * 64 WGs x 256 thr; per-thread weight slices in VGPRs (R2: conflicts=0).
//   * 4 grid barriers per step (h1 -> px/h -> f1/samples -> pg).
//   * fp64 accumulation everywhere (binary output: logits must match ref).
// =====================================================================

typedef unsigned int u32;

#define NWG   64
#define NT    256
#define NSTEP 8192

// ---- cross-WG exchange: relaxed agent-scope atomics (LLC-direct) ----
__device__ __forceinline__ double gld(const double* p) {
  return __hip_atomic_load(p, __ATOMIC_RELAXED, __HIP_MEMORY_SCOPE_AGENT);
}
__device__ __forceinline__ void gst(double* p, double v) {
  __hip_atomic_store(p, v, __ATOMIC_RELAXED, __HIP_MEMORY_SCOPE_AGENT);
}
__device__ __forceinline__ u32 gldu(const u32* p) {
  return __hip_atomic_load(p, __ATOMIC_RELAXED, __HIP_MEMORY_SCOPE_AGENT);
}
__device__ __forceinline__ void gstf(float* p, float v) {
  __hip_atomic_store(p, v, __ATOMIC_RELAXED, __HIP_MEMORY_SCOPE_AGENT);
}

// ---- grid barrier: counter arrivals + single broadcast word, all relaxed.
// __syncthreads before arrival drains each wave's vmcnt (sc1 stores are
// LLC-acked), so data is globally visible before the arrival RMW.
__device__ __forceinline__ void gbar(u32* cnt, u32* flg, u32 e) {
  __syncthreads();
  if (threadIdx.x == 0) {
    u32 prev = __hip_atomic_fetch_add(cnt, 1u, __ATOMIC_RELAXED, __HIP_MEMORY_SCOPE_AGENT);
    if (prev == e * (u32)NWG - 1u) {
      __hip_atomic_store(flg, e, __ATOMIC_RELAXED, __HIP_MEMORY_SCOPE_AGENT);
    } else {
      while (__hip_atomic_load(flg, __ATOMIC_RELAXED, __HIP_MEMORY_SCOPE_AGENT) < e) { }
    }
    asm volatile("" ::: "memory");   // compiler fence; HW needs none (sc1 everywhere)
  }
  __syncthreads();
}

// block-wide sum of one double per thread (deterministic order)
__device__ __forceinline__ double block_sum(double v, double* sred) {
  #pragma unroll
  for (int off = 32; off; off >>= 1) v += __shfl_down(v, off);
  __syncthreads();
  if ((threadIdx.x & 63) == 0) sred[threadIdx.x >> 6] = v;
  __syncthreads();
  return sred[0] + sred[1] + sred[2] + sred[3];
}

// ---------------------------------------------------------------------
// prep kernels (every launch; ~100us, fp64)
// ---------------------------------------------------------------------
__global__ void prep_zero(u32* hdr) {
  int i = blockIdx.x * 256 + threadIdx.x;
  if (i < 4096) hdr[i] = 0u;
}

// Wg2 = Wg @ W2   [256x512];  c1 = Wg@b2 + bg
__global__ __launch_bounds__(256) void prep_mm1(const float* __restrict__ Wg,
    const float* __restrict__ W2, const float* __restrict__ b2,
    const float* __restrict__ bg, double* __restrict__ Wg2d, double* __restrict__ c1d) {
  int i = threadIdx.x, j = blockIdx.x;
  double acc = 0.0;
  for (int k = 0; k < 256; k++) acc += (double)Wg[i * 256 + k] * (double)W2[k * 512 + j];
  Wg2d[(size_t)i * 512 + j] = acc;
  if (j == 0) {
    double c = 0.0;
    for (int k = 0; k < 256; k++) c += (double)Wg[i * 256 + k] * (double)b2[k];
    c1d[i] = c + (double)bg[i];
  }
}

// Wov = Wo @ Wv  [256x256];  c2 = Wo@bv + bo
__global__ __launch_bounds__(256) void prep_mm2(const float* __restrict__ Wo,
    const float* __restrict__ Wv, const float* __restrict__ bv,
    const float* __restrict__ bo, double* __restrict__ Wovd, double* __restrict__ c2d) {
  int i = threadIdx.x, j = blockIdx.x;
  double acc = 0.0;
  for (int k = 0; k < 256; k++) acc += (double)Wo[i * 256 + k] * (double)Wv[k * 256 + j];
  Wovd[i * 256 + j] = acc;
  if (j == 0) {
    double c = 0.0;
    for (int k = 0; k < 256; k++) c += (double)Wo[i * 256 + k] * (double)bv[k];
    c2d[i] = c + (double)bo[i];
  }
}

// Awg = (I + Wov) @ Wg2  [256x512];  c3 = (I+Wov)@c1 + c2
__global__ __launch_bounds__(256) void prep_mm3(const double* __restrict__ Wg2d,
    const double* __restrict__ Wovd, const double* __restrict__ c1d,
    const double* __restrict__ c2d, double* __restrict__ Awgd, double* __restrict__ c3d) {
  int i = threadIdx.x, j = blockIdx.x;
  double acc = Wg2d[(size_t)i * 512 + j];
  for (int k = 0; k < 256; k++) acc += Wovd[i * 256 + k] * Wg2d[(size_t)k * 512 + j];
  Awgd[(size_t)i * 512 + j] = acc;
  if (j == 0) {
    double c = c1d[i] + c2d[i];
    for (int k = 0; k < 256; k++) c += Wovd[i * 256 + k] * c1d[k];
    c3d[i] = c;
  }
}

// ---------------------------------------------------------------------
// main persistent kernel: 64 WGs x 256 threads, 8192 steps, 4 barriers/step
// ---------------------------------------------------------------------
__global__ __launch_bounds__(256) void sampler_main(
    const float* __restrict__ gnn, const float* __restrict__ u,
    const float* __restrict__ W1, const float* __restrict__ b1,
    const float* __restrict__ W2, const float* __restrict__ b2,
    const float* __restrict__ Wr, const float* __restrict__ br,
    const float* __restrict__ Wf1, const float* __restrict__ bf1,
    const float* __restrict__ Wf2, const float* __restrict__ bf2,
    const float* __restrict__ ln1g, const float* __restrict__ ln1b,
    const float* __restrict__ ln2g, const float* __restrict__ ln2b,
    const double* __restrict__ Awgd, const double* __restrict__ c3d,
    double* __restrict__ h1buf, double* __restrict__ pxbuf,
    double* __restrict__ hdbuf, double* __restrict__ f1buf,
    double* __restrict__ pgbuf, u32* __restrict__ hdr,
    float* __restrict__ out) {

  __shared__ double sin_[512];       // [ m_t ; g ]
  __shared__ double svec[512];       // staging: h1 (S2) then h (S3)
  __shared__ double sx  [256];       // x = ln1(px)
  __shared__ double sf1 [2048];      // f1 staging (S4)
  __shared__ double sprob[32];
  __shared__ double sred[8];
  __shared__ u32 ssamp[4];
  __shared__ int sidx;

  const int b = blockIdx.x, tid = threadIdx.x;
  u32* cnt    = &hdr[0];             // arrival counter (own line)
  u32* flg    = &hdr[32];            // broadcast epoch (own line)
  u32* counts = hdr + 64;            // [2][4] x 32-stride u32

  // ---- per-thread weight slices -> registers ----
  const int r1 = tid >> 5, l1 = tid & 31;     // S1: row 8b+r1
  float w1reg[16];
  #pragma unroll
  for (int k = 0; k < 16; k++) w1reg[k] = W1[(size_t)(8 * b + r1) * 512 + l1 + 32 * k];

  const int w2i = tid >> 6, l2 = tid & 63;    // S2/S4: row 4b+w2i
  double areg[8]; float w2reg[8];
  #pragma unroll
  for (int k = 0; k < 8; k++) {
    areg[k]  = Awgd[(size_t)(4 * b + w2i) * 512 + l2 + 64 * k];
    w2reg[k] = W2  [(size_t)(4 * b + w2i) * 512 + l2 + 64 * k];
  }
  const int r3 = tid >> 3, l3 = tid & 7;      // S3: row 32b+r3
  float f1reg[32], wrreg[32];
  #pragma unroll
  for (int k = 0; k < 32; k++) {
    f1reg[k] = Wf1[(size_t)(32 * b + r3) * 256 + l3 + 8 * k];
    wrreg[k] = Wr [(size_t)(32 * b + r3) * 256 + l3 + 8 * k];
  }
  float f2reg[32];
  #pragma unroll
  for (int k = 0; k < 32; k++) f2reg[k] = Wf2[(size_t)(4 * b + w2i) * 2048 + l2 + 64 * k];

  // per-thread constants
  const double ln1gv = (double)ln1g[tid], ln1bv = (double)ln1b[tid];
  const double ln2gv = (double)ln2g[tid], ln2bv = (double)ln2b[tid];
  const double b1v  = (double)b1 [8  * b + r1];
  const double b2v  = (double)b2 [4  * b + w2i];
  const double c3v  =          c3d[4  * b + w2i];
  const double bf1v = (double)bf1[32 * b + r3];
  const double brv  = (double)br [32 * b + r3];
  const double bf2v = (double)bf2[4  * b + w2i];

  // initial state: m(0) = gnn row 0, g0 = 0
  sin_[tid]       = (double)gnn[tid];
  sin_[256 + tid] = 0.0;
  __syncthreads();

  u32 ep = 0;
  for (int t = 0; t < NSTEP; ++t) {
    // ===== S1: h1 = relu(W1 @ [m;g] + b1), rows 8b..8b+7 =====
    {
      double acc = 0.0;
      #pragma unroll
      for (int k = 0; k < 16; k++) acc += (double)w1reg[k] * sin_[l1 + 32 * k];
      #pragma unroll
      for (int off = 16; off; off >>= 1) acc += __shfl_down(acc, off, 32);
      if (l1 == 0) { double v = acc + b1v; gst(&h1buf[8 * b + r1], (v > 0.0) ? v : 0.0); }
    }
    // prefetch u(t): this WG's 32 cols x 4 attempts
    float ureg = 0.0f;
    if (tid < 128) {
      int a = tid >> 5, jj = tid & 31;
      ureg = u[((size_t)t * 4 + a) * 2048 + 32 * b + jj];
    }
    // zero next parity's counters (readers done at B4(t-1))
    if (b == 0 && tid < 4)
      __hip_atomic_store(&counts[(((t + 1) & 1) * 4 + tid) * 32], 0u,
                         __ATOMIC_RELAXED, __HIP_MEMORY_SCOPE_AGENT);
    gbar(cnt, flg, ++ep);   // B1: h1 published

    // ===== S2: px = Awg@h1 + c3 ; h = W2@h1 + b2 =====
    svec[tid] = gld(&h1buf[tid]); svec[tid + 256] = gld(&h1buf[tid + 256]);
    __syncthreads();
    {
      double accA = 0.0, accH = 0.0;
      #pragma unroll
      for (int k = 0; k < 8; k++) {
        double hv = svec[l2 + 64 * k];
        accA += areg[k] * hv; accH += (double)w2reg[k] * hv;
      }
      #pragma unroll
      for (int off = 32; off; off >>= 1) { accA += __shfl_down(accA, off); accH += __shfl_down(accH, off); }
      if (l2 == 0) { gst(&pxbuf[4 * b + w2i], accA + c3v); gst(&hdbuf[4 * b + w2i], accH + b2v); }
    }
    sin_[tid] = (double)gnn[(size_t)((t + 1) & 4095) * 256 + tid];  // m(t+1)
    gbar(cnt, flg, ++ep);   // B2: px, h published

    // ===== S3: ln1 (redundant per WG), f1 slice, logits slice =====
    {
      double pxv = gld(&pxbuf[tid]);
      double hdv = gld(&hdbuf[tid]);   // issued with pxv: one LLC round-trip
      svec[tid] = hdv;                 // visible after block_sum's internal sync
      double mu  = block_sum(pxv, sred) * (1.0 / 256.0);
      double dv  = pxv - mu;
      double var = block_sum(dv * dv, sred) * (1.0 / 256.0);
      double rs  = 1.0 / sqrt(var + 1e-5);
      sx[tid] = dv * rs * ln1gv + ln1bv;
    }
    __syncthreads();
    {
      double accF = 0.0, accL = 0.0;
      #pragma unroll
      for (int k = 0; k < 32; k++) {
        int j = l3 + 8 * k;
        accF += (double)f1reg[k] * sx[j];
        accL += (double)wrreg[k] * svec[j];
      }
      #pragma unroll
      for (int off = 4; off; off >>= 1) { accF += __shfl_down(accF, off, 8); accL += __shfl_down(accL, off, 8); }
      if (l3 == 0) {
        double fv = accF + bf1v;
        gst(&f1buf[32 * b + r3], (fv > 0.0) ? fv : 0.0);
        sprob[r3] = 1.0 / (1.0 + exp(-(accL + brv)));
      }
    }
    __syncthreads();
    if (tid < 128) {                  // samples + exact integer counts
      int a = tid >> 5;
      bool pred = ((double)ureg < sprob[tid & 31]);
      unsigned long long bal = __ballot(pred);
      int l64 = tid & 63;
      if (l64 == 0) {
        u32 mm = (u32)(bal & 0xffffffffull);
        ssamp[a] = mm; atomicAdd(&counts[((t & 1) * 4 + a) * 32], (u32)__popc(mm));
      } else if (l64 == 32) {
        u32 mm = (u32)(bal >> 32);
        ssamp[a] = mm; atomicAdd(&counts[((t & 1) * 4 + a) * 32], (u32)__popc(mm));
      }
    }
    gbar(cnt, flg, ++ep);   // B3: f1, counts published

    // ===== S4: pg = x + Wf2@f1 + bf2 ; emit row =====
    if (tid == 0) {
      int idx = 0;
      for (int a = 3; a >= 0; a--) {
        u32 c = gldu(&counts[((t & 1) * 4 + a) * 32]);
        bool va = (c == 0u) || (c >= 2u && c <= 6u);
        if (va) idx = a;
      }
      sidx = idx;
    }
    {
      double tmp[8];
      #pragma unroll
      for (int k = 0; k < 8; k++) tmp[k] = gld(&f1buf[tid + 256 * k]);
      #pragma unroll
      for (int k = 0; k < 8; k++) sf1[tid + 256 * k] = tmp[k];
    }
    __syncthreads();
    {
      double acc = 0.0;
      #pragma unroll
      for (int k = 0; k < 32; k++) acc += (double)f2reg[k] * sf1[l2 + 64 * k];
      #pragma unroll
      for (int off = 32; off; off >>= 1) acc += __shfl_down(acc, off);
      if (l2 == 0) gst(&pgbuf[4 * b + w2i], acc + sx[4 * b + w2i] + bf2v);
    }
    if (tid < 32) {
      u32 mm = ssamp[sidx];
      gstf(&out[(size_t)t * 2048 + 32 * b + tid], ((mm >> tid) & 1u) ? 1.0f : 0.0f);
    }
    gbar(cnt, flg, ++ep);   // B4: pg published

    // ===== S5: g = ln2(pg) (redundant per WG) =====
    {
      double pgv = gld(&pgbuf[tid]);
      double mu  = block_sum(pgv, sred) * (1.0 / 256.0);
      double dv  = pgv - mu;
      double var = block_sum(dv * dv, sred) * (1.0 / 256.0);
      double rs  = 1.0 / sqrt(var + 1e-5);
      sin_[256 + tid] = dv * rs * ln2gv + ln2bv;
    }
    __syncthreads();
  }
}

// ---------------------------------------------------------------------
extern "C" void kernel_launch(void* const* d_in, const int* in_sizes, int n_in,
                              void* d_out, int out_size, void* d_ws, size_t ws_size,
                              hipStream_t stream) {
  const float* gnn = (const float*)d_in[0];
  const float* u   = (const float*)d_in[2];
  const float* W1  = (const float*)d_in[3];
  const float* b1  = (const float*)d_in[4];
  const float* W2  = (const float*)d_in[5];
  const float* b2  = (const float*)d_in[6];
  const float* Wr  = (const float*)d_in[7];
  const float* br  = (const float*)d_in[8];
  const float* Wg  = (const float*)d_in[9];
  const float* bg  = (const float*)d_in[10];
  const float* Wv  = (const float*)d_in[11];
  const float* bv  = (const float*)d_in[12];
  const float* Wo  = (const float*)d_in[13];
  const float* bo  = (const float*)d_in[14];
  const float* Wf1 = (const float*)d_in[15];
  const float* bf1 = (const float*)d_in[16];
  const float* Wf2 = (const float*)d_in[17];
  const float* bf2 = (const float*)d_in[18];
  const float* ln1g = (const float*)d_in[19];
  const float* ln1b = (const float*)d_in[20];
  const float* ln2g = (const float*)d_in[21];
  const float* ln2b = (const float*)d_in[22];
  float* out = (float*)d_out;

  // workspace: 16KB header (cnt/flg/counts), then fp64 buffers
  u32* hdr = (u32*)d_ws;
  double* base  = (double*)((char*)d_ws + 16384);
  double* h1buf = base;            // 512
  double* pxbuf = h1buf + 512;     // 256
  double* hdbuf = pxbuf + 256;     // 256
  double* f1buf = hdbuf + 256;     // 2048
  double* pgbuf = f1buf + 2048;    // 256
  double* c1d   = pgbuf + 256;     // 256
  double* c2d   = c1d + 256;       // 256
  double* c3d   = c2d + 256;       // 256
  double* Wg2d  = c3d + 256;       // 131072
  double* Wovd  = Wg2d + 131072;   // 65536
  double* Awgd  = Wovd + 65536;    // 131072

  hipLaunchKernelGGL(prep_zero, dim3(16), dim3(256), 0, stream, hdr);
  hipLaunchKernelGGL(prep_mm1, dim3(512), dim3(256), 0, stream, Wg, W2, b2, bg, Wg2d, c1d);
  hipLaunchKernelGGL(prep_mm2, dim3(256), dim3(256), 0, stream, Wo, Wv, bv, bo, Wovd, c2d);
  hipLaunchKernelGGL(prep_mm3, dim3(512), dim3(256), 0, stream, Wg2d, Wovd, c1d, c2d, Awgd, c3d);
  hipLaunchKernelGGL(sampler_main, dim3(NWG), dim3(NT), 0, stream,
                     gnn, u, W1, b1, W2, b2, Wr, br, Wf1, bf1, Wf2, bf2,
                     ln1g, ln1b, ln2g, ln2b, Awgd, c3d,
                     h1buf, pxbuf, hdbuf, f1buf, pgbuf, hdr, out);
}

// Round 4
// 85832.581 us; speedup vs baseline: 2.1988x; 1.2776x over previous
//
#include <hip/hip_runtime.h>

// =====================================================================
// AutoregressiveSubsetSampler — persistent cooperative kernel, MI355X.
// Round 4: K-distributed partial-sum dataflow -> 2 grid barriers/step
// (was 4), fp64 atomic-add reductions (parallel across 256 addresses,
// no single-line RMW serialization), 64-slot contiguous flag-array
// barrier with relaxed sc1 stores/polls (no counter RMW, no broadcast
// hop, no acquire invalidates).
//
// Per step t:
//  stage A: h1 slice local (rows 8b..8b+8) -> px/h partials atomicAdd -> B1
//  stage B: read px,h (4KB); ln1 redundant -> x; f1 slice LOCAL (LDS);
//           logits slice -> sampling -> counts; pg partial atomicAdd;
//           WG1 zeroes next-parity accumulators -> B2
//  stage C: read pg (2KB); ln2 redundant -> g; pick attempt; write row.
// All fp64 on the logit-critical chain (binary output: ~1e-13 margin).
// =====================================================================

typedef unsigned int u32;

#define NWG   64
#define NT    256
#define NSTEP 8192

// ---- relaxed agent-scope (LLC-direct, cache-bypassing) ops ----
__device__ __forceinline__ double gld(const double* p) {
  return __hip_atomic_load(p, __ATOMIC_RELAXED, __HIP_MEMORY_SCOPE_AGENT);
}
__device__ __forceinline__ void gst(double* p, double v) {
  __hip_atomic_store(p, v, __ATOMIC_RELAXED, __HIP_MEMORY_SCOPE_AGENT);
}
__device__ __forceinline__ u32 gldu(const u32* p) {
  return __hip_atomic_load(p, __ATOMIC_RELAXED, __HIP_MEMORY_SCOPE_AGENT);
}
__device__ __forceinline__ void gstu(u32* p, u32 v) {
  __hip_atomic_store(p, v, __ATOMIC_RELAXED, __HIP_MEMORY_SCOPE_AGENT);
}
__device__ __forceinline__ void gstf(float* p, float v) {
  __hip_atomic_store(p, v, __ATOMIC_RELAXED, __HIP_MEMORY_SCOPE_AGENT);
}
// fp64 atomic add -> global_atomic_add_f64 (HW instr on gfx90a+/gfx950)
__device__ __forceinline__ void gadd(double* p, double v) {
  unsafeAtomicAdd(p, v);
}

// ---- flag-array grid barrier: contiguous 64 u32 slots (2 cachelines).
// __syncthreads drains each wave's vmcnt before s_barrier, so all of the
// WG's global stores/atomics are LLC-acked before lane 0 raises its flag.
// Poll: 64 lanes, relaxed loads (no invalidates), exit when all >= e.
__device__ __forceinline__ void gbar(u32* flags, u32 e) {
  __syncthreads();
  if (threadIdx.x == 0) gstu(&flags[blockIdx.x], e);
  if (threadIdx.x < 64) {
    while (gldu(&flags[threadIdx.x]) < e) { }
  }
  asm volatile("" ::: "memory");
  __syncthreads();
}

// block-wide sum of one double per thread (deterministic order per WG;
// redundant WGs execute identical sequences -> bitwise-identical results)
__device__ __forceinline__ double block_sum(double v, double* sred) {
  #pragma unroll
  for (int off = 32; off; off >>= 1) v += __shfl_down(v, off);
  __syncthreads();
  if ((threadIdx.x & 63) == 0) sred[threadIdx.x >> 6] = v;
  __syncthreads();
  return sred[0] + sred[1] + sred[2] + sred[3];
}

// ---------------------------------------------------------------------
// prep kernels (every launch; ~100us, fp64)
// ---------------------------------------------------------------------
__global__ void prep_zero(u32* hdr) {
  int i = blockIdx.x * 256 + threadIdx.x;
  if (i < 4096) hdr[i] = 0u;   // flags + counts + px/h/pg accumulators (16KB)
}

// Wg2 = Wg @ W2   [256x512];  c1 = Wg@b2 + bg
__global__ __launch_bounds__(256) void prep_mm1(const float* __restrict__ Wg,
    const float* __restrict__ W2, const float* __restrict__ b2,
    const float* __restrict__ bg, double* __restrict__ Wg2d, double* __restrict__ c1d) {
  int i = threadIdx.x, j = blockIdx.x;
  double acc = 0.0;
  for (int k = 0; k < 256; k++) acc += (double)Wg[i * 256 + k] * (double)W2[k * 512 + j];
  Wg2d[(size_t)i * 512 + j] = acc;
  if (j == 0) {
    double c = 0.0;
    for (int k = 0; k < 256; k++) c += (double)Wg[i * 256 + k] * (double)b2[k];
    c1d[i] = c + (double)bg[i];
  }
}

// Wov = Wo @ Wv  [256x256];  c2 = Wo@bv + bo
__global__ __launch_bounds__(256) void prep_mm2(const float* __restrict__ Wo,
    const float* __restrict__ Wv, const float* __restrict__ bv,
    const float* __restrict__ bo, double* __restrict__ Wovd, double* __restrict__ c2d) {
  int i = threadIdx.x, j = blockIdx.x;
  double acc = 0.0;
  for (int k = 0; k < 256; k++) acc += (double)Wo[i * 256 + k] * (double)Wv[k * 256 + j];
  Wovd[i * 256 + j] = acc;
  if (j == 0) {
    double c = 0.0;
    for (int k = 0; k < 256; k++) c += (double)Wo[i * 256 + k] * (double)bv[k];
    c2d[i] = c + (double)bo[i];
  }
}

// Awg = (I + Wov) @ Wg2  [256x512];  c3 = (I+Wov)@c1 + c2
__global__ __launch_bounds__(256) void prep_mm3(const double* __restrict__ Wg2d,
    const double* __restrict__ Wovd, const double* __restrict__ c1d,
    const double* __restrict__ c2d, double* __restrict__ Awgd, double* __restrict__ c3d) {
  int i = threadIdx.x, j = blockIdx.x;
  double acc = Wg2d[(size_t)i * 512 + j];
  for (int k = 0; k < 256; k++) acc += Wovd[i * 256 + k] * Wg2d[(size_t)k * 512 + j];
  Awgd[(size_t)i * 512 + j] = acc;
  if (j == 0) {
    double c = c1d[i] + c2d[i];
    for (int k = 0; k < 256; k++) c += Wovd[i * 256 + k] * c1d[k];
    c3d[i] = c;
  }
}

// ---------------------------------------------------------------------
// main persistent kernel: 64 WGs x 256 threads, 8192 steps, 2 barriers/step
// ---------------------------------------------------------------------
__global__ __launch_bounds__(256) void sampler_main(
    const float* __restrict__ gnn, const float* __restrict__ u,
    const float* __restrict__ W1, const float* __restrict__ b1,
    const float* __restrict__ W2, const float* __restrict__ b2,
    const float* __restrict__ Wr, const float* __restrict__ br,
    const float* __restrict__ Wf1, const float* __restrict__ bf1,
    const float* __restrict__ Wf2, const float* __restrict__ bf2,
    const float* __restrict__ ln1g, const float* __restrict__ ln1b,
    const float* __restrict__ ln2g, const float* __restrict__ ln2b,
    const double* __restrict__ Awgd, const double* __restrict__ c3d,
    double* __restrict__ pxbuf, double* __restrict__ hbuf,
    double* __restrict__ pgbuf, u32* __restrict__ hdr,
    float* __restrict__ out) {

  __shared__ double smg[512];        // [ m_t ; g ]
  __shared__ double sh1[8];          // local h1 slice (k-cols 8b..8b+8)
  __shared__ double sx [256];        // x = ln1(px)
  __shared__ double shh[256];        // h broadcast
  __shared__ double sf1[32];         // local f1 slice
  __shared__ double sprob[32];
  __shared__ double sred[8];
  __shared__ u32 ssamp[4];
  __shared__ int sidx;

  const int b = blockIdx.x, tid = threadIdx.x;
  u32* flags  = hdr;                 // 64 contiguous u32
  u32* counts = hdr + 96;            // [2][4] u32, stride 32

  // ---- per-thread weight slices -> registers ----
  const int r1 = tid >> 5, l1 = tid & 31;     // stage A: W1 row 8b+r1
  float w1reg[16];
  #pragma unroll
  for (int k = 0; k < 16; k++) w1reg[k] = W1[(size_t)(8 * b + r1) * 512 + l1 + 32 * k];

  // K-col slices: this thread owns OUTPUT index tid, K-cols 8b..8b+8
  double areg[8]; float w2reg[8];
  #pragma unroll
  for (int k = 0; k < 8; k++) {
    areg[k]  = Awgd[(size_t)tid * 512 + 8 * b + k];
    w2reg[k] = W2  [(size_t)tid * 512 + 8 * b + k];
  }
  const int r3 = tid >> 3, l3 = tid & 7;      // stage B: rows 32b+r3
  float f1reg[32], wrreg[32];
  #pragma unroll
  for (int k = 0; k < 32; k++) {
    f1reg[k] = Wf1[(size_t)(32 * b + r3) * 256 + l3 + 8 * k];
    wrreg[k] = Wr [(size_t)(32 * b + r3) * 256 + l3 + 8 * k];
  }
  // Wf2 K-col slice: output tid, K-cols 32b..32b+32
  float f2reg[32];
  #pragma unroll
  for (int k = 0; k < 32; k++) f2reg[k] = Wf2[(size_t)tid * 2048 + 32 * b + k];

  // per-thread constants
  const double ln1gv = (double)ln1g[tid], ln1bv = (double)ln1b[tid];
  const double ln2gv = (double)ln2g[tid], ln2bv = (double)ln2b[tid];
  const double b1v  = (double)b1 [8 * b + r1];
  const double b2v  = (double)b2 [tid];
  const double c3v  =          c3d[tid];
  const double bf1v = (double)bf1[32 * b + r3];
  const double brv  = (double)br [32 * b + r3];
  const double bf2v = (double)bf2[tid];

  // initial state: m(0) = gnn row 0, g0 = 0
  smg[tid]       = (double)gnn[tid];
  smg[256 + tid] = 0.0;
  __syncthreads();

  for (int t = 0; t < NSTEP; ++t) {
    const int p = t & 1;
    double* pxp = pxbuf + p * 256;
    double* hp_ = hbuf  + p * 256;
    double* pgp = pgbuf + p * 256;
    u32*   cntp = counts + p * 4 * 32;

    // ================= stage A =================
    float ureg = 0.0f;                          // u(t) prefetch (used stage B)
    if (tid < 128)
      ureg = u[((size_t)t * 4 + (tid >> 5)) * 2048 + 32 * b + (tid & 31)];
    {
      double acc = 0.0;                         // h1 slice, rows 8b..8b+7
      #pragma unroll
      for (int k = 0; k < 16; k++) acc += (double)w1reg[k] * smg[l1 + 32 * k];
      #pragma unroll
      for (int off = 16; off; off >>= 1) acc += __shfl_down(acc, off, 32);
      if (l1 == 0) { double v = acc + b1v; sh1[r1] = (v > 0.0) ? v : 0.0; }
    }
    __syncthreads();
    {
      double pxv = 0.0, hv = 0.0;               // K-partials for px, h
      #pragma unroll
      for (int k = 0; k < 8; k++) {
        double h1k = sh1[k];
        pxv += areg[k] * h1k; hv += (double)w2reg[k] * h1k;
      }
      if (b == 0) { pxv += c3v; hv += b2v; }
      gadd(&pxp[tid], pxv); gadd(&hp_[tid], hv);
    }
    gbar(flags, 2 * t + 1);   // B1: px, h complete

    // ================= stage B =================
    double pxv   = gld(&pxp[tid]);
    double hv    = gld(&hp_[tid]);
    double mnext = (double)gnn[(size_t)((t + 1) & 4095) * 256 + tid];
    shh[tid] = hv;
    double xv;
    {
      double mu  = block_sum(pxv, sred) * (1.0 / 256.0);
      double dv  = pxv - mu;
      double var = block_sum(dv * dv, sred) * (1.0 / 256.0);
      xv = dv * (1.0 / sqrt(var + 1e-5)) * ln1gv + ln1bv;
    }
    sx[tid]  = xv;
    smg[tid] = mnext;                            // m(t+1); h1 dot done pre-B1
    __syncthreads();
    {
      double accF = 0.0, accL = 0.0;             // f1 rows + logit rows 32b+r3
      #pragma unroll
      for (int k = 0; k < 32; k++) {
        int j = l3 + 8 * k;
        accF += (double)f1reg[k] * sx[j];
        accL += (double)wrreg[k] * shh[j];
      }
      #pragma unroll
      for (int off = 4; off; off >>= 1) { accF += __shfl_down(accF, off, 8); accL += __shfl_down(accL, off, 8); }
      if (l3 == 0) {
        double fv = accF + bf1v;
        sf1[r3]   = (fv > 0.0) ? fv : 0.0;       // local f1 slice -> LDS only
        sprob[r3] = 1.0 / (1.0 + exp(-(accL + brv)));
      }
    }
    __syncthreads();
    if (tid < 128) {                             // sampling + exact counts
      int a = tid >> 5;
      bool pred = ((double)ureg < sprob[tid & 31]);
      unsigned long long bal = __ballot(pred);
      int l64 = tid & 63;
      if (l64 == 0) {
        u32 mm = (u32)(bal & 0xffffffffull);
        ssamp[a] = mm; atomicAdd(&cntp[a * 32], (u32)__popc(mm));
      } else if (l64 == 32) {
        u32 mm = (u32)(bal >> 32);
        ssamp[a] = mm; atomicAdd(&cntp[a * 32], (u32)__popc(mm));
      }
    }
    {
      double pgv = 0.0;                          // pg K-partial
      #pragma unroll
      for (int k = 0; k < 32; k++) pgv += (double)f2reg[k] * sf1[k];
      if (b == 0) pgv += xv + bf2v;
      gadd(&pgp[tid], pgv);
    }
    if (b == 1) {                                // zero next-parity accums
      gst(&pxbuf[(1 - p) * 256 + tid], 0.0);
      gst(&hbuf [(1 - p) * 256 + tid], 0.0);
      gst(&pgbuf[(1 - p) * 256 + tid], 0.0);
      if (tid < 4) gstu(&counts[(1 - p) * 4 * 32 + tid * 32], 0u);
    }
    gbar(flags, 2 * t + 2);   // B2: pg, counts complete

    // ================= stage C =================
    double pgv = gld(&pgp[tid]);
    if (tid == 0) {
      int idx = 0;
      for (int a = 3; a >= 0; a--) {
        u32 c = gldu(&cntp[a * 32]);
        if (c == 0u || (c >= 2u && c <= 6u)) idx = a;
      }
      sidx = idx;
    }
    {
      double mu  = block_sum(pgv, sred) * (1.0 / 256.0);
      double dv  = pgv - mu;
      double var = block_sum(dv * dv, sred) * (1.0 / 256.0);
      smg[256 + tid] = dv * (1.0 / sqrt(var + 1e-5)) * ln2gv + ln2bv;
    }
    __syncthreads();
    if (tid < 32) {
      u32 mm = ssamp[sidx];
      gstf(&out[(size_t)t * 2048 + 32 * b + tid], ((mm >> tid) & 1u) ? 1.0f : 0.0f);
    }
  }
}

// ---------------------------------------------------------------------
extern "C" void kernel_launch(void* const* d_in, const int* in_sizes, int n_in,
                              void* d_out, int out_size, void* d_ws, size_t ws_size,
                              hipStream_t stream) {
  const float* gnn = (const float*)d_in[0];
  const float* u   = (const float*)d_in[2];
  const float* W1  = (const float*)d_in[3];
  const float* b1  = (const float*)d_in[4];
  const float* W2  = (const float*)d_in[5];
  const float* b2  = (const float*)d_in[6];
  const float* Wr  = (const float*)d_in[7];
  const float* br  = (const float*)d_in[8];
  const float* Wg  = (const float*)d_in[9];
  const float* bg  = (const float*)d_in[10];
  const float* Wv  = (const float*)d_in[11];
  const float* bv  = (const float*)d_in[12];
  const float* Wo  = (const float*)d_in[13];
  const float* bo  = (const float*)d_in[14];
  const float* Wf1 = (const float*)d_in[15];
  const float* bf1 = (const float*)d_in[16];
  const float* Wf2 = (const float*)d_in[17];
  const float* bf2 = (const float*)d_in[18];
  const float* ln1g = (const float*)d_in[19];
  const float* ln1b = (const float*)d_in[20];
  const float* ln2g = (const float*)d_in[21];
  const float* ln2b = (const float*)d_in[22];
  float* out = (float*)d_out;

  // workspace: [0,16KB) = flags/counts (4KB) + px/h/pg accumulators (12KB)
  u32* hdr = (u32*)d_ws;
  double* pxbuf = (double*)((char*)d_ws + 4096);   // [2][256]
  double* hbuf  = pxbuf + 512;                     // [2][256]
  double* pgbuf = hbuf  + 512;                     // [2][256]
  double* base  = (double*)((char*)d_ws + 16384);
  double* c1d   = base;            // 256
  double* c2d   = c1d + 256;       // 256
  double* c3d   = c2d + 256;       // 256
  double* Wg2d  = c3d + 256;       // 131072
  double* Wovd  = Wg2d + 131072;   // 65536
  double* Awgd  = Wovd + 65536;    // 131072

  hipLaunchKernelGGL(prep_zero, dim3(16), dim3(256), 0, stream, hdr);
  hipLaunchKernelGGL(prep_mm1, dim3(512), dim3(256), 0, stream, Wg, W2, b2, bg, Wg2d, c1d);
  hipLaunchKernelGGL(prep_mm2, dim3(256), dim3(256), 0, stream, Wo, Wv, bv, bo, Wovd, c2d);
  hipLaunchKernelGGL(prep_mm3, dim3(512), dim3(256), 0, stream, Wg2d, Wovd, c1d, c2d, Awgd, c3d);
  hipLaunchKernelGGL(sampler_main, dim3(NWG), dim3(NT), 0, stream,
                     gnn, u, W1, b1, W2, b2, Wr, br, Wf1, bf1, Wf2, bf2,
                     ln1g, ln1b, ln2g, ln2b, Awgd, c3d,
                     pxbuf, hbuf, pgbuf, hdr, out);
}